// Round 12
// baseline (322.915 us; speedup 1.0000x reference)
//
#include <hip/hip_runtime.h>

namespace {

constexpr int H = 512;
constexpr int W = 512;
constexpr int HW = H * W;
constexpr int PPS = 8;    // planes per canny set
constexpr int NP = 16;    // total planes (2 sets x 8)
constexpr int TX = 64;    // tile width (dnms/result)
constexpr int TY = 16;    // tile height (dnms/result): 4 adjacent rows/thread
constexpr int STY = 16;   // smooth tile height
constexpr int NBLK = (W / TX) * (H / TY) * NP;   // 4096
constexpr int HBLK = NBLK / 2;                   // 2048 per set
constexpr float PI_F = 3.14159265358979323846f;
constexpr int NBINS = 1024;                 // median bins over [0,2)
constexpr float BIN_SCALE = 512.0f;

__device__ __forceinline__ float hsw(float x) {
    float t = fminf(fmaxf(x + 3.0f, 0.0f), 6.0f);
    return x * t * (1.0f / 6.0f);
}

__device__ __forceinline__ const float* plane_ptr(const float* s1, const float* s2, int p) {
    return (p < PPS) ? (s1 + (size_t)p * HW) : (s2 + (size_t)(p - PPS) * HW);
}

__device__ __forceinline__ float wave_max(float v) {
    for (int o = 32; o > 0; o >>= 1) v = fmaxf(v, __shfl_down(v, o, 64));
    return v;
}
__device__ __forceinline__ float wave_min(float v) {
    for (int o = 32; o > 0; o >>= 1) v = fminf(v, __shfl_down(v, o, 64));
    return v;
}

// minimax atan on [0,1], err ~2e-7
__device__ __forceinline__ float atan_poly(float t) {
    float z = t * t;
    float p = -0.01172120f;
    p = p * z + 0.05265332f;
    p = p * z - 0.11643287f;
    p = p * z + 0.19354346f;
    p = p * z - 0.33262347f;
    p = p * z + 0.99997726f;
    return t * p;
}

// 4-to-1 mux with static code (no runtime-indexed arrays)
__device__ __forceinline__ float sel4(int idx, float v0, float v1, float v2, float v3) {
    float a = (idx & 1) ? v1 : v0;
    float b = (idx & 1) ? v3 : v2;
    return (idx & 2) ? b : a;
}

// One adaptive-smoothing iteration; 16-row tile (base col j0-4, float4 staging).
// First dispatch also zeroes the median histogram + done counters (hist != nullptr).
__global__ void K_smooth(const float* __restrict__ s1, const float* __restrict__ s2,
                         float* __restrict__ fout, unsigned* __restrict__ hist,
                         unsigned* __restrict__ ctr) {
    int tid = threadIdx.y * 64 + threadIdx.x;
    if (hist) {
        int bid = (blockIdx.z * gridDim.y + blockIdx.y) * gridDim.x + blockIdx.x;
        if (bid < (NP * NBINS) / 256) hist[bid * 256 + tid] = 0;
        if (bid == 64 && tid < 2) ctr[tid] = 0;
    }
    int p = blockIdx.z;
    const float* f = plane_ptr(s1, s2, p);
    int j0 = blockIdx.x * 64, i0 = blockIdx.y * STY;
    __shared__ float fs[STY + 4][72];   // f at (i0-2+y, j0-4+x), clip on border blocks
    __shared__ float ws[STY + 2][66];   // w(clip(i0-1+y), clip(j0-1+x))

    bool interior = (i0 >= 2) && (i0 + STY + 1 <= H - 1) && (j0 >= 4) && (j0 + 67 <= W - 1);

    if (interior) {
        const float* fb = f + (i0 - 2) * W + (j0 - 4);
        for (int e = tid; e < (STY + 4) * 18; e += 256) {
            int y = e / 18, x4 = e % 18;
            float4 v = *(const float4*)(fb + y * W + x4 * 4);
            *(float4*)&fs[y][x4 * 4] = v;
        }
        __syncthreads();
        for (int e = tid; e < (STY + 2) * 66; e += 256) {
            int y = e / 66, x = e % 66;
            float gx = 0.5f * (fs[y + 2][x + 3] - fs[y][x + 3]);
            float gy = 0.5f * (fs[y + 1][x + 4] - fs[y + 1][x + 2]);
            ws[y][x] = __expf(-(gx * gx + gy * gy) * (1.0f / 200.0f));
        }
    } else {
        for (int e = tid; e < (STY + 4) * 72; e += 256) {
            int y = e / 72, x = e % 72;
            int gi = min(max(i0 - 2 + y, 0), H - 1);
            int gj = min(max(j0 - 4 + x, 0), W - 1);
            fs[y][x] = f[gi * W + gj];
        }
        __syncthreads();
        for (int e = tid; e < (STY + 2) * 66; e += 256) {
            int y = e / 66, x = e % 66;
            int r = min(max(i0 - 1 + y, 0), H - 1);   // w evaluated at CLIPPED coords
            int c = min(max(j0 - 1 + x, 0), W - 1);
            int yr = r - (i0 - 2), xc = c - (j0 - 4);
            int ym = max(r - 1, 0) - (i0 - 2), yp = min(r + 1, H - 1) - (i0 - 2);
            int xm = max(c - 1, 0) - (j0 - 4), xp = min(c + 1, W - 1) - (j0 - 4);
            float gx = 0.5f * (fs[yp][xc] - fs[ym][xc]);
            float gy = 0.5f * (fs[yr][xp] - fs[yr][xm]);
            ws[y][x] = __expf(-(gx * gx + gy * gy) * (1.0f / 200.0f));
        }
    }
    __syncthreads();

    int yl = threadIdx.y * 4;
    int xl = threadIdx.x;
    float rn[6], rd[6];
#pragma unroll
    for (int k = 0; k < 6; k++) {
        float w0 = ws[yl + k][xl], w1 = ws[yl + k][xl + 1], w2 = ws[yl + k][xl + 2];
        float fA = fs[yl + k + 1][xl + 3], fB = fs[yl + k + 1][xl + 4], fC = fs[yl + k + 1][xl + 5];
        rn[k] = fA * w0 + fB * w1 + fC * w2;
        rd[k] = w0 + w1 + w2;
    }
    size_t base = (size_t)p * HW + (i0 + yl) * W + (j0 + xl);
#pragma unroll
    for (int k = 0; k < 4; k++) {
        fout[base + (size_t)k * W] =
            (rn[k] + rn[k + 1] + rn[k + 2]) / fmaxf(rd[k] + rd[k + 1] + rd[k + 2], 1e-8f);
    }
}

// fused derivatives + NMS (2-direction softmax) + median histogram.
// LAST block (device done-counter) also computes per-plane medians + per-set sup max.
__global__ void K_dnms(const float* __restrict__ blur, float* __restrict__ sup,
                       unsigned* __restrict__ hist, float* __restrict__ pmax,
                       float* __restrict__ medv, float* __restrict__ mx,
                       unsigned* __restrict__ ctr) {
    int p = blockIdx.z;
    const float* f = blur + (size_t)p * HW;
    int j0 = blockIdx.x * TX, i0 = blockIdx.y * TY;
    __shared__ float fs0[TY + 4][72];   // ZERO-padded blur at (i0-2+y, j0-4+x)
    __shared__ float ms[TY + 2][TX + 2];
    __shared__ unsigned histS[NBINS];
    __shared__ float wred[4], wred2[4];
    __shared__ unsigned part[16][16];
    __shared__ unsigned lastFlag;
    int tid = threadIdx.y * 64 + threadIdx.x;

    bool interior = (i0 >= 2) && (i0 + TY + 1 <= H - 1) && (j0 >= 4) && (j0 + 67 <= W - 1);

    for (int e = tid; e < NBINS; e += 256) histS[e] = 0;
    if (interior) {
        const float* fb = f + (i0 - 2) * W + (j0 - 4);
        for (int e = tid; e < (TY + 4) * 18; e += 256) {
            int y = e / 18, x4 = e % 18;
            float4 v = *(const float4*)(fb + y * W + x4 * 4);
            *(float4*)&fs0[y][x4 * 4] = v;
        }
    } else {
        for (int e = tid; e < (TY + 4) * 72; e += 256) {
            int y = e / 72, x = e % 72;
            int gi = i0 - 2 + y, gj = j0 - 4 + x;
            fs0[y][x] = (gi >= 0 && gi < H && gj >= 0 && gj < W) ? f[gi * W + gj] : 0.0f;
        }
    }
    __syncthreads();

    int xl = threadIdx.x;
    int yb = threadIdx.y * 4;

    // interior pixels: this thread's 4 adjacent rows; derivatives in registers
    float fv[6][3];
#pragma unroll
    for (int rr = 0; rr < 6; rr++)
#pragma unroll
        for (int cc = 0; cc < 3; cc++)
            fv[rr][cc] = fs0[yb + 1 + rr][xl + 3 + cc];

    float exk[4], eyk[4];
#pragma unroll
    for (int k = 0; k < 4; k++) {
        float xmm = fv[k][0], xm0 = fv[k][1], xmp = fv[k][2];
        float x0m = fv[k + 1][0], x0p = fv[k + 1][2];
        float xpm = fv[k + 2][0], xp0 = fv[k + 2][1], xpp = fv[k + 2][2];
        float ex = (xmp - xmm) + 2.0f * (x0p - x0m) + (xpp - xpm);
        float ey = (xpm + 2.0f * xp0 + xpp) - (xmm + 2.0f * xm0 + xmp);
        float e45 = -2.0f * xmm - xm0 - x0m + x0p + xp0 + 2.0f * xpp;
        float e135 = xm0 + 2.0f * xmp - x0m + x0p - 2.0f * xpm - xp0;
        ms[yb + 1 + k][xl + 1] = sqrtf(ex * ex + ey * ey + e45 * e45 + e135 * e135);
        exk[k] = ex;
        eyk[k] = ey;
    }

    // halo mag entries (164 of them)
    if (tid < 2 * (TX + 2) + 2 * TY) {
        int y, x;
        if (tid < TX + 2) { y = 0; x = tid; }
        else if (tid < 2 * (TX + 2)) { y = TY + 1; x = tid - (TX + 2); }
        else if (tid < 2 * (TX + 2) + TY) { y = tid - 2 * (TX + 2) + 1; x = 0; }
        else { y = tid - (2 * (TX + 2) + TY) + 1; x = TX + 1; }
        int rr, cc;
        if (interior) { rr = y + 1; cc = x + 3; }
        else {
            int r = min(max(i0 - 1 + y, 0), H - 1);
            int c = min(max(j0 - 1 + x, 0), W - 1);
            rr = r - i0 + 2; cc = c - j0 + 4;
        }
        float xmm = fs0[rr - 1][cc - 1], xm0 = fs0[rr - 1][cc], xmp = fs0[rr - 1][cc + 1];
        float x0m = fs0[rr][cc - 1], x0p = fs0[rr][cc + 1];
        float xpm = fs0[rr + 1][cc - 1], xp0 = fs0[rr + 1][cc], xpp = fs0[rr + 1][cc + 1];
        float ex = (xmp - xmm) + 2.0f * (x0p - x0m) + (xpp - xpm);
        float ey = (xpm + 2.0f * xp0 + xpp) - (xmm + 2.0f * xm0 + xmp);
        float e45 = -2.0f * xmm - xm0 - x0m + x0p + xp0 + 2.0f * xpp;
        float e135 = xm0 + 2.0f * xmp - x0m + x0p - 2.0f * xpm - xp0;
        ms[y][x] = sqrtf(ex * ex + ey * ey + e45 * e45 + e135 * e135);
    }
    __syncthreads();

    // 6x3 mag register block covering the 4 pixels' 3x3 neighborhoods
    float msr[6][3];
#pragma unroll
    for (int rr = 0; rr < 6; rr++)
#pragma unroll
        for (int cc = 0; cc < 3; cc++)
            msr[rr][cc] = ms[yb + rr][xl + cc];

    float bmax = 0.0f;
#pragma unroll
    for (int k = 0; k < 4; k++) {
        float ex = exk[k], ey = eyk[k];

        // fast mod-pi line angle
        float ax = fabsf(ex), ay = fabsf(ey);
        float mn = fminf(ax, ay), mxv = fmaxf(ax, ay);
        float tq = (mxv > 0.0f) ? __fdividef(mn, mxv) : 0.0f;
        float pang = atan_poly(tq);
        if (ay > ax) pang = 1.57079632679f - pang;
        bool obtuse = ((__float_as_uint(ex) ^ __float_as_uint(ey)) & 0x80000000u) != 0u;
        float a = obtuse ? PI_F - pang : pang;

        // nearest + second-nearest direction; other two weigh <= e^(-25*pi)
        float fa = a * 1.27323954474f;          // a * 4/pi  in [0,4]
        float nf = floorf(fa + 0.5f);           // 0..4
        float diff = a - nf * 0.78539816340f;
        float delta = fabsf(diff);
        int n = (int)nf & 3;
        int m = ((diff >= 0.0f) ? (int)nf + 1 : (int)nf - 1) & 3;
        float t = __expf(200.0f * delta - 78.5398163397f);   // e^{-100(pi/4-2delta)} <= 1
        float u = __fdividef(1.0f, 1.0f + t);

        float m0 = msr[k + 1][1];
        float n1a = msr[k + 1][0], n1b = msr[k][0], n1c = msr[k][1], n1d = msr[k][2];
        float n2a = msr[k + 1][2], n2b = msr[k + 2][2], n2c = msr[k + 2][1], n2d = msr[k + 2][0];
        float n1n = sel4(n, n1a, n1b, n1c, n1d);
        float n2n = sel4(n, n2a, n2b, n2c, n2d);
        float n1m = sel4(m, n1a, n1b, n1c, n1d);
        float n2m = sel4(m, n2a, n2b, n2c, n2d);

        float g1n = __expf((n1n - m0) * 10.0f);
        float g2n = __expf((n2n - m0) * 10.0f);
        float g1m = __expf((n1m - m0) * 10.0f);
        float g2m = __expf((n2m - m0) * 10.0f);
        float swn = __fdividef(1.0f, 1.0f + g1n + g2n);
        float swm = __fdividef(1.0f, 1.0f + g1m + g2m);
        float s = m0 * u * (swn + t * swm);

        sup[(size_t)p * HW + (i0 + yb + k) * W + (j0 + xl)] = s;
        bmax = fmaxf(bmax, s);

        // median histogram: sob quantized, bins over [0,2)
        float sv = 0.5f * (ax + ay);
        int bin = min((int)(sv * BIN_SCALE), NBINS - 1);
        atomicAdd(&histS[bin], 1u);
    }

    float wv = wave_max(bmax);
    if ((tid & 63) == 0) wred[tid >> 6] = wv;
    __syncthreads();
    int bflat = (blockIdx.z * gridDim.y + blockIdx.y) * gridDim.x + blockIdx.x;
    if (tid == 0) pmax[bflat] = fmaxf(fmaxf(wred[0], wred[1]), fmaxf(wred[2], wred[3]));
    for (int e = tid; e < NBINS; e += 256)
        if (histS[e]) atomicAdd(&hist[p * NBINS + e], histS[e]);

    // publish, then last block computes medians + sup maxima
    __syncthreads();
    if (tid == 0) {
        __threadfence();
        lastFlag = (atomicAdd(&ctr[0], 1u) == NBLK - 1) ? 1u : 0u;
    }
    __syncthreads();
    if (lastFlag) {
        __threadfence();
        // medians: 16 planes x 16 threads (each sums a 64-bin chunk)
        int q = tid >> 4, g = tid & 15;
        const unsigned* hp = hist + q * NBINS;
        unsigned s = 0;
        for (int j = 0; j < 64; j++) s += hp[g * 64 + j];
        part[q][g] = s;
        __syncthreads();
        if (g == 0) {
            const int k = (HW - 1) / 2;
            int cum = 0, chunk = 15;
            for (int j = 0; j < 16; j++) {
                int c = (int)part[q][j];
                if (cum + c > k) { chunk = j; break; }
                cum += c;
            }
            int bin = chunk * 64 + 63;
            for (int j = 0; j < 64; j++) {
                int c = (int)hp[chunk * 64 + j];
                if (cum + c > k) { bin = chunk * 64 + j; break; }
                cum += c;
            }
            medv[q] = ((float)bin + 0.5f) * (1.0f / BIN_SCALE);
        }
        // per-set sup max
        float v0 = -1e30f, v1 = -1e30f;
        for (int i = tid; i < HBLK; i += 256) {
            v0 = fmaxf(v0, pmax[i]);
            v1 = fmaxf(v1, pmax[HBLK + i]);
        }
        v0 = wave_max(v0);
        v1 = wave_max(v1);
        if ((tid & 63) == 0) { wred[tid >> 6] = v0; wred2[tid >> 6] = v1; }
        __syncthreads();
        if (tid == 0) {
            mx[0] = fmaxf(fmaxf(wred[0], wred[1]), fmaxf(wred[2], wred[3]));
            mx[1] = fmaxf(fmaxf(wred2[0], wred2[1]), fmaxf(wred2[2], wred2[3]));
        }
    }
}

// hysteresis combine + dilation + sobel(original) blend; base col j0-4, float4 staging.
// LAST block reduces prmax/prmin -> rmaxv/rminv scalars.
__global__ void K_result(const float* __restrict__ sup, const float* __restrict__ im1,
                         const float* __restrict__ im2, const float* __restrict__ medv,
                         const float* __restrict__ sg1, const float* __restrict__ ew1,
                         const float* __restrict__ sg2, const float* __restrict__ ew2,
                         const float* __restrict__ mx, float* __restrict__ res,
                         float* __restrict__ prmax, float* __restrict__ prmin,
                         float* __restrict__ rmaxv, float* __restrict__ rminv,
                         unsigned* __restrict__ ctr) {
    int p = blockIdx.z;
    int s = p >> 3;
    float med = 0.125f * (medv[s * PPS + 0] + medv[s * PPS + 1] + medv[s * PPS + 2] +
                          medv[s * PPS + 3] + medv[s * PPS + 4] + medv[s * PPS + 5] +
                          medv[s * PPS + 6] + medv[s * PPS + 7]);
    float sgin = (s == 0) ? sg1[0] : sg2[0];
    float ewin = (s == 0) ? ew1[0] : ew2[0];
    float sig = 1.0f - 1.0f / (1.0f + __expf(-sgin));
    float lo = fminf(fmaxf((1.0f - sig) * med, 0.001f), 1.0f);
    float hi = fminf(fmaxf((1.0f + sig) * med, 0.001f), 1.0f);
    float wg = 1.0f / (1.0f + __expf(-ewin));
    float m = mx[s];
    float inv = 1.0f / ((m > 0.0f) ? m : 1.0f);

    const float* sp = sup + (size_t)p * HW;
    const float* op = plane_ptr(im1, im2, p);
    int j0 = blockIdx.x * TX, i0 = blockIdx.y * TY;
    __shared__ float hs2[TY + 2][72];   // hsw(sup_norm - hi) at (i0-1+y, j0-4+x), 0 outside
    __shared__ float og[TY + 2][72];    // original image, 0 outside
    __shared__ float ssn[TY][TX];       // normalized sup, interior pixels
    __shared__ float wredx[4], wredn[4];
    __shared__ unsigned lastFlag;
    int tid = threadIdx.y * 64 + threadIdx.x;

    bool interior = (i0 >= 1) && (i0 + TY <= H - 1) && (j0 >= 4) && (j0 + 67 <= W - 1);

    if (interior) {
        const float* spb = sp + (i0 - 1) * W + (j0 - 4);
        const float* opb = op + (i0 - 1) * W + (j0 - 4);
        for (int e = tid; e < (TY + 2) * 18; e += 256) {
            int y = e / 18, x4 = e % 18;
            float4 a = *(const float4*)(spb + y * W + x4 * 4);
            float4 o = *(const float4*)(opb + y * W + x4 * 4);
            float sv0 = a.x * inv, sv1 = a.y * inv, sv2 = a.z * inv, sv3 = a.w * inv;
            float4 hv;
            hv.x = hsw(sv0 - hi); hv.y = hsw(sv1 - hi);
            hv.z = hsw(sv2 - hi); hv.w = hsw(sv3 - hi);
            *(float4*)&hs2[y][x4 * 4] = hv;
            *(float4*)&og[y][x4 * 4] = o;
            if (y >= 1 && y <= TY) {
                int c0 = x4 * 4;
                if (c0 + 0 >= 4 && c0 + 0 <= 67) ssn[y - 1][c0 - 4] = sv0;
                if (c0 + 1 >= 4 && c0 + 1 <= 67) ssn[y - 1][c0 - 3] = sv1;
                if (c0 + 2 >= 4 && c0 + 2 <= 67) ssn[y - 1][c0 - 2] = sv2;
                if (c0 + 3 >= 4 && c0 + 3 <= 67) ssn[y - 1][c0 - 1] = sv3;
            }
        }
    } else {
        for (int e = tid; e < (TY + 2) * 72; e += 256) {
            int y = e / 72, x = e % 72;
            int gi = i0 - 1 + y, gj = j0 - 4 + x;
            float h = 0.0f, o = 0.0f;
            if (gi >= 0 && gi < H && gj >= 0 && gj < W) {
                float sv = sp[gi * W + gj] * inv;
                h = hsw(sv - hi);
                o = op[gi * W + gj];
                if (y >= 1 && y <= TY && x >= 4 && x <= 67) ssn[y - 1][x - 4] = sv;
            }
            hs2[y][x] = h;
            og[y][x] = o;
        }
    }
    __syncthreads();

    int yl = threadIdx.y * 4;
    int xl = threadIdx.x;
    float hrow[6], ddr[6], ssr[6];
#pragma unroll
    for (int k = 0; k < 6; k++) {
        float a = hs2[yl + k][xl + 3], bq = hs2[yl + k][xl + 4], c = hs2[yl + k][xl + 5];
        hrow[k] = a + bq + c;
        float oa = og[yl + k][xl + 3], ob = og[yl + k][xl + 4], oc = og[yl + k][xl + 5];
        ddr[k] = oc - oa;
        ssr[k] = oa + 2.0f * ob + oc;
    }

    float bmx = -1e30f, bmn = 1e30f;
    size_t gbase = (size_t)p * HW + (i0 + yl) * W + (j0 + xl);
#pragma unroll
    for (int k = 0; k < 4; k++) {
        float sn = ssn[yl + k][xl];
        float Sh = hs2[yl + k + 1][xl + 4];
        float Sl = hsw(sn - lo);
        float dil = hrow[k] + hrow[k + 1] + hrow[k + 2];
        float pre = sn * (Sh + Sl) + dil * Sl * (1.0f - Sh);
        float sob = 0.5f * fabsf(ddr[k] + 2.0f * ddr[k + 1] + ddr[k + 2]) +
                    0.5f * fabsf(ssr[k + 2] - ssr[k]);
        float r = (1.0f - wg) * pre + wg * sob;
        res[gbase + (size_t)k * W] = r;
        bmx = fmaxf(bmx, r);
        bmn = fminf(bmn, r);
    }

    float vx = wave_max(bmx), vn = wave_min(bmn);
    if ((tid & 63) == 0) { wredx[tid >> 6] = vx; wredn[tid >> 6] = vn; }
    __syncthreads();
    int bflat = (blockIdx.z * gridDim.y + blockIdx.y) * gridDim.x + blockIdx.x;
    if (tid == 0) {
        prmax[bflat] = fmaxf(fmaxf(wredx[0], wredx[1]), fmaxf(wredx[2], wredx[3]));
        prmin[bflat] = fminf(fminf(wredn[0], wredn[1]), fminf(wredn[2], wredn[3]));
        __threadfence();
        lastFlag = (atomicAdd(&ctr[1], 1u) == NBLK - 1) ? 1u : 0u;
    }
    __syncthreads();
    if (lastFlag) {
        __threadfence();
        float vx0 = -1e30f, vn0 = 1e30f, vx1 = -1e30f, vn1 = 1e30f;
        for (int i = tid; i < HBLK; i += 256) {
            vx0 = fmaxf(vx0, prmax[i]);
            vn0 = fminf(vn0, prmin[i]);
            vx1 = fmaxf(vx1, prmax[HBLK + i]);
            vn1 = fminf(vn1, prmin[HBLK + i]);
        }
        vx0 = wave_max(vx0); vn0 = wave_min(vn0);
        vx1 = wave_max(vx1); vn1 = wave_min(vn1);
        __syncthreads();   // wredx/wredn reuse
        if ((tid & 63) == 0) { wredx[tid >> 6] = vx0; wredn[tid >> 6] = vn0; }
        __syncthreads();
        if (tid == 0) {
            rmaxv[0] = fmaxf(fmaxf(wredx[0], wredx[1]), fmaxf(wredx[2], wredx[3]));
            rminv[0] = fminf(fminf(wredn[0], wredn[1]), fminf(wredn[2], wredn[3]));
        }
        __syncthreads();
        if ((tid & 63) == 0) { wredx[tid >> 6] = vx1; wredn[tid >> 6] = vn1; }
        __syncthreads();
        if (tid == 0) {
            rmaxv[1] = fmaxf(fmaxf(wredx[0], wredx[1]), fmaxf(wredx[2], wredx[3]));
            rminv[1] = fminf(fminf(wredn[0], wredn[1]), fminf(wredn[2], wredn[3]));
        }
    }
}

// final normalize + combine; pure streaming, float4 I/O
__global__ void K_final(const float* __restrict__ res, const float* __restrict__ rmaxv,
                        const float* __restrict__ rminv, float* __restrict__ out) {
    float mx1 = rmaxv[0], mn1 = rminv[0];
    float mx2 = rmaxv[1], mn2 = rminv[1];
    float is1 = 1.0f / (mx1 - mn1);
    float is2 = 1.0f / (mx2 - mn2);

    int col4 = blockIdx.x * 64 + threadIdx.x;    // float4 column, 0..127
    int i0 = blockIdx.y * 16 + threadIdx.y * 4;  // 4 rows per thread
    int p = blockIdx.z;                          // 0..7
    const float4* r1p = (const float4*)(res + (size_t)p * HW);
    const float4* r2p = (const float4*)(res + (size_t)(p + PPS) * HW);
    float4* outc = (float4*)(out) + (size_t)p * (HW / 4);
    float4* out1 = (float4*)(out) + (size_t)(PPS + p) * (HW / 4);
    float4* out2 = (float4*)(out) + (size_t)(2 * PPS + p) * (HW / 4);

#pragma unroll
    for (int k = 0; k < 4; k++) {
        int row = i0 + k;
        float4 a = r1p[row * (W / 4) + col4];
        float4 b = r2p[row * (W / 4) + col4];
        float4 m1v, m2v, mcv;
        m1v.x = (a.x - mn1) * is1; m1v.y = (a.y - mn1) * is1;
        m1v.z = (a.z - mn1) * is1; m1v.w = (a.w - mn1) * is1;
        m2v.x = (b.x - mn2) * is2; m2v.y = (b.y - mn2) * is2;
        m2v.z = (b.z - mn2) * is2; m2v.w = (b.w - mn2) * is2;
        mcv.x = m1v.x + m2v.x - 2.0f * m1v.x * m2v.x;
        mcv.y = m1v.y + m2v.y - 2.0f * m1v.y * m2v.y;
        mcv.z = m1v.z + m2v.z - 2.0f * m1v.z * m2v.z;
        mcv.w = m1v.w + m2v.w - 2.0f * m1v.w * m2v.w;
        outc[row * (W / 4) + col4] = mcv;
        out1[row * (W / 4) + col4] = m1v;
        out2[row * (W / 4) + col4] = m2v;
    }
}

}  // namespace

extern "C" void kernel_launch(void* const* d_in, const int* in_sizes, int n_in,
                              void* d_out, int out_size, void* d_ws, size_t ws_size,
                              hipStream_t stream) {
    const float* img1 = (const float*)d_in[0];
    const float* img2 = (const float*)d_in[1];
    const float* sg1 = (const float*)d_in[2];
    const float* ew1 = (const float*)d_in[3];
    const float* sg2 = (const float*)d_in[4];
    const float* ew2 = (const float*)d_in[5];
    float* out = (float*)d_out;

    float* A = (float*)d_ws;                             // ping / blurred
    float* B = A + (size_t)NP * HW;                      // pong / res
    float* C = B + (size_t)NP * HW;                      // sup
    unsigned* hist = (unsigned*)(C + (size_t)NP * HW);   // NP*NBINS
    float* medv = (float*)(hist + NP * NBINS);           // 16
    float* mx = medv + NP;             // 2
    float* rmaxv = mx + 2;             // 2
    float* rminv = rmaxv + 2;          // 2
    unsigned* ctr = (unsigned*)(rminv + 2);   // 2 done-counters
    float* pmax = (float*)(ctr + 2);   // NBLK
    float* prmax = pmax + NBLK;        // NBLK
    float* prmin = prmax + NBLK;       // NBLK

    dim3 blk(64, 4, 1);
    dim3 grdT(W / TX, H / TY, NP);     // dnms / result (4096 blocks)
    dim3 grdS(W / 64, H / STY, NP);    // smooth
    dim3 grdF(W / 256, H / 16, PPS);   // final (512 blocks, float4, 4 rows/thread)

    // adaptive smoothing: 3 iterations  in->A, A->B, B->A  (blurred -> A)
    // first dispatch also zeroes the median histogram + done counters
    K_smooth<<<grdS, blk, 0, stream>>>(img1, img2, A, hist, ctr);
    K_smooth<<<grdS, blk, 0, stream>>>(A, A + (size_t)PPS * HW, B, nullptr, nullptr);
    K_smooth<<<grdS, blk, 0, stream>>>(B, B + (size_t)PPS * HW, A, nullptr, nullptr);

    // fused derivs+NMS+median-hist; last block computes medv + mx
    K_dnms<<<grdT, blk, 0, stream>>>(A, C, hist, pmax, medv, mx, ctr);

    // result -> B; last block reduces prmax/prmin -> rmaxv/rminv
    K_result<<<grdT, blk, 0, stream>>>(C, img1, img2, medv, sg1, ew1, sg2, ew2, mx,
                                       B, prmax, prmin, rmaxv, rminv, ctr);

    // final: normalize + combine, float4 I/O
    K_final<<<grdF, blk, 0, stream>>>(B, rmaxv, rminv, out);
}

// Round 13
// 109.429 us; speedup vs baseline: 2.9509x; 2.9509x over previous
//
#include <hip/hip_runtime.h>

namespace {

constexpr int H = 512;
constexpr int W = 512;
constexpr int HW = H * W;
constexpr int PPS = 8;    // planes per canny set
constexpr int NP = 16;    // total planes (2 sets x 8)
constexpr int TX = 64;    // tile width (dnms/result)
constexpr int TY = 16;    // tile height (dnms/result): 4 adjacent rows/thread
constexpr int STY = 16;   // smooth tile height
constexpr int NBLK = (W / TX) * (H / TY) * NP;   // 4096
constexpr int HBLK = NBLK / 2;                   // 2048 per set
constexpr float PI_F = 3.14159265358979323846f;
constexpr int NBINS = 1024;                 // median bins over [0,2)
constexpr float BIN_SCALE = 512.0f;

__device__ __forceinline__ float hsw(float x) {
    float t = fminf(fmaxf(x + 3.0f, 0.0f), 6.0f);
    return x * t * (1.0f / 6.0f);
}

__device__ __forceinline__ const float* plane_ptr(const float* s1, const float* s2, int p) {
    return (p < PPS) ? (s1 + (size_t)p * HW) : (s2 + (size_t)(p - PPS) * HW);
}

__device__ __forceinline__ float wave_max(float v) {
    for (int o = 32; o > 0; o >>= 1) v = fmaxf(v, __shfl_down(v, o, 64));
    return v;
}
__device__ __forceinline__ float wave_min(float v) {
    for (int o = 32; o > 0; o >>= 1) v = fminf(v, __shfl_down(v, o, 64));
    return v;
}

// minimax atan on [0,1], err ~2e-7
__device__ __forceinline__ float atan_poly(float t) {
    float z = t * t;
    float p = -0.01172120f;
    p = p * z + 0.05265332f;
    p = p * z - 0.11643287f;
    p = p * z + 0.19354346f;
    p = p * z - 0.33262347f;
    p = p * z + 0.99997726f;
    return t * p;
}

// 4-to-1 mux with static code (no runtime-indexed arrays)
__device__ __forceinline__ float sel4(int idx, float v0, float v1, float v2, float v3) {
    float a = (idx & 1) ? v1 : v0;
    float b = (idx & 1) ? v3 : v2;
    return (idx & 2) ? b : a;
}

// One adaptive-smoothing iteration; 16-row tile (base col j0-4, float4 staging).
// First dispatch also zeroes the median histogram (hist != nullptr).
__global__ void K_smooth(const float* __restrict__ s1, const float* __restrict__ s2,
                         float* __restrict__ fout, unsigned* __restrict__ hist) {
    int tid = threadIdx.y * 64 + threadIdx.x;
    if (hist) {
        int bid = (blockIdx.z * gridDim.y + blockIdx.y) * gridDim.x + blockIdx.x;
        if (bid < (NP * NBINS) / 256) hist[bid * 256 + tid] = 0;
    }
    int p = blockIdx.z;
    const float* f = plane_ptr(s1, s2, p);
    int j0 = blockIdx.x * 64, i0 = blockIdx.y * STY;
    __shared__ float fs[STY + 4][72];   // f at (i0-2+y, j0-4+x), clip on border blocks
    __shared__ float ws[STY + 2][66];   // w(clip(i0-1+y), clip(j0-1+x))

    bool interior = (i0 >= 2) && (i0 + STY + 1 <= H - 1) && (j0 >= 4) && (j0 + 67 <= W - 1);

    if (interior) {
        const float* fb = f + (i0 - 2) * W + (j0 - 4);
        for (int e = tid; e < (STY + 4) * 18; e += 256) {
            int y = e / 18, x4 = e % 18;
            float4 v = *(const float4*)(fb + y * W + x4 * 4);
            *(float4*)&fs[y][x4 * 4] = v;
        }
        __syncthreads();
        for (int e = tid; e < (STY + 2) * 66; e += 256) {
            int y = e / 66, x = e % 66;
            float gx = 0.5f * (fs[y + 2][x + 3] - fs[y][x + 3]);
            float gy = 0.5f * (fs[y + 1][x + 4] - fs[y + 1][x + 2]);
            ws[y][x] = __expf(-(gx * gx + gy * gy) * (1.0f / 200.0f));
        }
    } else {
        for (int e = tid; e < (STY + 4) * 72; e += 256) {
            int y = e / 72, x = e % 72;
            int gi = min(max(i0 - 2 + y, 0), H - 1);
            int gj = min(max(j0 - 4 + x, 0), W - 1);
            fs[y][x] = f[gi * W + gj];
        }
        __syncthreads();
        for (int e = tid; e < (STY + 2) * 66; e += 256) {
            int y = e / 66, x = e % 66;
            int r = min(max(i0 - 1 + y, 0), H - 1);   // w evaluated at CLIPPED coords
            int c = min(max(j0 - 1 + x, 0), W - 1);
            int yr = r - (i0 - 2), xc = c - (j0 - 4);
            int ym = max(r - 1, 0) - (i0 - 2), yp = min(r + 1, H - 1) - (i0 - 2);
            int xm = max(c - 1, 0) - (j0 - 4), xp = min(c + 1, W - 1) - (j0 - 4);
            float gx = 0.5f * (fs[yp][xc] - fs[ym][xc]);
            float gy = 0.5f * (fs[yr][xp] - fs[yr][xm]);
            ws[y][x] = __expf(-(gx * gx + gy * gy) * (1.0f / 200.0f));
        }
    }
    __syncthreads();

    int yl = threadIdx.y * 4;
    int xl = threadIdx.x;
    float rn[6], rd[6];
#pragma unroll
    for (int k = 0; k < 6; k++) {
        float w0 = ws[yl + k][xl], w1 = ws[yl + k][xl + 1], w2 = ws[yl + k][xl + 2];
        float fA = fs[yl + k + 1][xl + 3], fB = fs[yl + k + 1][xl + 4], fC = fs[yl + k + 1][xl + 5];
        rn[k] = fA * w0 + fB * w1 + fC * w2;
        rd[k] = w0 + w1 + w2;
    }
    size_t base = (size_t)p * HW + (i0 + yl) * W + (j0 + xl);
#pragma unroll
    for (int k = 0; k < 4; k++) {
        fout[base + (size_t)k * W] =
            (rn[k] + rn[k + 1] + rn[k + 2]) / fmaxf(rd[k] + rd[k + 1] + rd[k + 2], 1e-8f);
    }
}

// fused derivatives + NMS (2-direction softmax) + median histogram.
// Interior derivatives live in registers; only mag goes through LDS.
__global__ void K_dnms(const float* __restrict__ blur, float* __restrict__ sup,
                       unsigned* __restrict__ hist, float* __restrict__ pmax) {
    int p = blockIdx.z;
    const float* f = blur + (size_t)p * HW;
    int j0 = blockIdx.x * TX, i0 = blockIdx.y * TY;
    __shared__ float fs0[TY + 4][72];   // ZERO-padded blur at (i0-2+y, j0-4+x)
    __shared__ float ms[TY + 2][TX + 2];
    __shared__ unsigned histS[NBINS];
    __shared__ float wred[4];
    int tid = threadIdx.y * 64 + threadIdx.x;

    bool interior = (i0 >= 2) && (i0 + TY + 1 <= H - 1) && (j0 >= 4) && (j0 + 67 <= W - 1);

    for (int e = tid; e < NBINS; e += 256) histS[e] = 0;
    if (interior) {
        const float* fb = f + (i0 - 2) * W + (j0 - 4);
        for (int e = tid; e < (TY + 4) * 18; e += 256) {
            int y = e / 18, x4 = e % 18;
            float4 v = *(const float4*)(fb + y * W + x4 * 4);
            *(float4*)&fs0[y][x4 * 4] = v;
        }
    } else {
        for (int e = tid; e < (TY + 4) * 72; e += 256) {
            int y = e / 72, x = e % 72;
            int gi = i0 - 2 + y, gj = j0 - 4 + x;
            fs0[y][x] = (gi >= 0 && gi < H && gj >= 0 && gj < W) ? f[gi * W + gj] : 0.0f;
        }
    }
    __syncthreads();

    int xl = threadIdx.x;
    int yb = threadIdx.y * 4;

    // interior pixels: this thread's 4 adjacent rows; derivatives in registers
    float fv[6][3];
#pragma unroll
    for (int rr = 0; rr < 6; rr++)
#pragma unroll
        for (int cc = 0; cc < 3; cc++)
            fv[rr][cc] = fs0[yb + 1 + rr][xl + 3 + cc];

    float exk[4], eyk[4];
#pragma unroll
    for (int k = 0; k < 4; k++) {
        float xmm = fv[k][0], xm0 = fv[k][1], xmp = fv[k][2];
        float x0m = fv[k + 1][0], x0p = fv[k + 1][2];
        float xpm = fv[k + 2][0], xp0 = fv[k + 2][1], xpp = fv[k + 2][2];
        float ex = (xmp - xmm) + 2.0f * (x0p - x0m) + (xpp - xpm);
        float ey = (xpm + 2.0f * xp0 + xpp) - (xmm + 2.0f * xm0 + xmp);
        float e45 = -2.0f * xmm - xm0 - x0m + x0p + xp0 + 2.0f * xpp;
        float e135 = xm0 + 2.0f * xmp - x0m + x0p - 2.0f * xpm - xp0;
        ms[yb + 1 + k][xl + 1] = sqrtf(ex * ex + ey * ey + e45 * e45 + e135 * e135);
        exk[k] = ex;
        eyk[k] = ey;
    }

    // halo mag entries (164 of them)
    if (tid < 2 * (TX + 2) + 2 * TY) {
        int y, x;
        if (tid < TX + 2) { y = 0; x = tid; }
        else if (tid < 2 * (TX + 2)) { y = TY + 1; x = tid - (TX + 2); }
        else if (tid < 2 * (TX + 2) + TY) { y = tid - 2 * (TX + 2) + 1; x = 0; }
        else { y = tid - (2 * (TX + 2) + TY) + 1; x = TX + 1; }
        int rr, cc;
        if (interior) { rr = y + 1; cc = x + 3; }
        else {
            int r = min(max(i0 - 1 + y, 0), H - 1);
            int c = min(max(j0 - 1 + x, 0), W - 1);
            rr = r - i0 + 2; cc = c - j0 + 4;
        }
        float xmm = fs0[rr - 1][cc - 1], xm0 = fs0[rr - 1][cc], xmp = fs0[rr - 1][cc + 1];
        float x0m = fs0[rr][cc - 1], x0p = fs0[rr][cc + 1];
        float xpm = fs0[rr + 1][cc - 1], xp0 = fs0[rr + 1][cc], xpp = fs0[rr + 1][cc + 1];
        float ex = (xmp - xmm) + 2.0f * (x0p - x0m) + (xpp - xpm);
        float ey = (xpm + 2.0f * xp0 + xpp) - (xmm + 2.0f * xm0 + xmp);
        float e45 = -2.0f * xmm - xm0 - x0m + x0p + xp0 + 2.0f * xpp;
        float e135 = xm0 + 2.0f * xmp - x0m + x0p - 2.0f * xpm - xp0;
        ms[y][x] = sqrtf(ex * ex + ey * ey + e45 * e45 + e135 * e135);
    }
    __syncthreads();

    // 6x3 mag register block covering the 4 pixels' 3x3 neighborhoods
    float msr[6][3];
#pragma unroll
    for (int rr = 0; rr < 6; rr++)
#pragma unroll
        for (int cc = 0; cc < 3; cc++)
            msr[rr][cc] = ms[yb + rr][xl + cc];

    float bmax = 0.0f;
#pragma unroll
    for (int k = 0; k < 4; k++) {
        float ex = exk[k], ey = eyk[k];

        // fast mod-pi line angle
        float ax = fabsf(ex), ay = fabsf(ey);
        float mn = fminf(ax, ay), mxv = fmaxf(ax, ay);
        float tq = (mxv > 0.0f) ? __fdividef(mn, mxv) : 0.0f;
        float pang = atan_poly(tq);
        if (ay > ax) pang = 1.57079632679f - pang;
        bool obtuse = ((__float_as_uint(ex) ^ __float_as_uint(ey)) & 0x80000000u) != 0u;
        float a = obtuse ? PI_F - pang : pang;

        // nearest + second-nearest direction; other two weigh <= e^(-25*pi)
        float fa = a * 1.27323954474f;          // a * 4/pi  in [0,4]
        float nf = floorf(fa + 0.5f);           // 0..4
        float diff = a - nf * 0.78539816340f;
        float delta = fabsf(diff);
        int n = (int)nf & 3;
        int m = ((diff >= 0.0f) ? (int)nf + 1 : (int)nf - 1) & 3;
        float t = __expf(200.0f * delta - 78.5398163397f);   // e^{-100(pi/4-2delta)} <= 1
        float u = __fdividef(1.0f, 1.0f + t);

        float m0 = msr[k + 1][1];
        float n1a = msr[k + 1][0], n1b = msr[k][0], n1c = msr[k][1], n1d = msr[k][2];
        float n2a = msr[k + 1][2], n2b = msr[k + 2][2], n2c = msr[k + 2][1], n2d = msr[k + 2][0];
        float n1n = sel4(n, n1a, n1b, n1c, n1d);
        float n2n = sel4(n, n2a, n2b, n2c, n2d);
        float n1m = sel4(m, n1a, n1b, n1c, n1d);
        float n2m = sel4(m, n2a, n2b, n2c, n2d);

        float g1n = __expf((n1n - m0) * 10.0f);
        float g2n = __expf((n2n - m0) * 10.0f);
        float g1m = __expf((n1m - m0) * 10.0f);
        float g2m = __expf((n2m - m0) * 10.0f);
        float swn = __fdividef(1.0f, 1.0f + g1n + g2n);
        float swm = __fdividef(1.0f, 1.0f + g1m + g2m);
        float s = m0 * u * (swn + t * swm);

        sup[(size_t)p * HW + (i0 + yb + k) * W + (j0 + xl)] = s;
        bmax = fmaxf(bmax, s);

        // median histogram: sob quantized, bins over [0,2)
        float sv = 0.5f * (ax + ay);
        int bin = min((int)(sv * BIN_SCALE), NBINS - 1);
        atomicAdd(&histS[bin], 1u);
    }

    float wv = wave_max(bmax);
    if ((tid & 63) == 0) wred[tid >> 6] = wv;
    __syncthreads();
    if (tid == 0) {
        int bflat = (blockIdx.z * gridDim.y + blockIdx.y) * gridDim.x + blockIdx.x;
        pmax[bflat] = fmaxf(fmaxf(wred[0], wred[1]), fmaxf(wred[2], wred[3]));
    }
    for (int e = tid; e < NBINS; e += 256)
        if (histS[e]) atomicAdd(&hist[p * NBINS + e], histS[e]);
}

// blocks 0..15: per-plane median pick; blocks 16..17: per-set sup max reduce
__global__ void K_stats(const unsigned* __restrict__ hist, const float* __restrict__ pmax,
                        float* __restrict__ medv, float* __restrict__ mx) {
    int b = blockIdx.x;
    int t = threadIdx.x;
    if (b < NP) {
        __shared__ unsigned sums[256];
        const unsigned* hp = hist + b * NBINS;
        unsigned s = 0;
        for (int q = 0; q < NBINS / 256; q++) s += hp[t * (NBINS / 256) + q];
        sums[t] = s;
        __syncthreads();
        for (int off = 1; off < 256; off <<= 1) {
            unsigned v = (t >= off) ? sums[t - off] : 0u;
            __syncthreads();
            sums[t] += v;
            __syncthreads();
        }
        const int k = (HW - 1) / 2;
        unsigned base = (t == 0) ? 0u : sums[t - 1];
        if ((int)base <= k && k < (int)sums[t]) {
            int cum = (int)base;
            int bin = t * (NBINS / 256);
            for (int q = 0; q < NBINS / 256; q++) {
                int c = (int)hp[t * (NBINS / 256) + q];
                if (cum + c > k) { bin = t * (NBINS / 256) + q; break; }
                cum += c;
            }
            medv[b] = ((float)bin + 0.5f) * (1.0f / BIN_SCALE);
        }
    } else {
        __shared__ float red[256];
        int s = b - NP;
        const float* base = pmax + s * HBLK;
        float v = -1e30f;
        for (int i = t; i < HBLK; i += 256) v = fmaxf(v, base[i]);
        red[t] = v;
        __syncthreads();
        for (int sft = 128; sft > 0; sft >>= 1) {
            if (t < sft) red[t] = fmaxf(red[t], red[t + sft]);
            __syncthreads();
        }
        if (t == 0) mx[s] = red[0];
    }
}

// hysteresis combine + dilation + sobel(original) blend; base col j0-4, float4 staging
__global__ void K_result(const float* __restrict__ sup, const float* __restrict__ im1,
                         const float* __restrict__ im2, const float* __restrict__ medv,
                         const float* __restrict__ sg1, const float* __restrict__ ew1,
                         const float* __restrict__ sg2, const float* __restrict__ ew2,
                         const float* __restrict__ mx, float* __restrict__ res,
                         float* __restrict__ prmax, float* __restrict__ prmin) {
    int p = blockIdx.z;
    int s = p >> 3;
    float med = 0.125f * (medv[s * PPS + 0] + medv[s * PPS + 1] + medv[s * PPS + 2] +
                          medv[s * PPS + 3] + medv[s * PPS + 4] + medv[s * PPS + 5] +
                          medv[s * PPS + 6] + medv[s * PPS + 7]);
    float sgin = (s == 0) ? sg1[0] : sg2[0];
    float ewin = (s == 0) ? ew1[0] : ew2[0];
    float sig = 1.0f - 1.0f / (1.0f + __expf(-sgin));
    float lo = fminf(fmaxf((1.0f - sig) * med, 0.001f), 1.0f);
    float hi = fminf(fmaxf((1.0f + sig) * med, 0.001f), 1.0f);
    float wg = 1.0f / (1.0f + __expf(-ewin));
    float m = mx[s];
    float inv = 1.0f / ((m > 0.0f) ? m : 1.0f);

    const float* sp = sup + (size_t)p * HW;
    const float* op = plane_ptr(im1, im2, p);
    int j0 = blockIdx.x * TX, i0 = blockIdx.y * TY;
    __shared__ float hs2[TY + 2][72];   // hsw(sup_norm - hi) at (i0-1+y, j0-4+x), 0 outside
    __shared__ float og[TY + 2][72];    // original image, 0 outside
    __shared__ float ssn[TY][TX];       // normalized sup, interior pixels
    __shared__ float wredx[4], wredn[4];
    int tid = threadIdx.y * 64 + threadIdx.x;

    bool interior = (i0 >= 1) && (i0 + TY <= H - 1) && (j0 >= 4) && (j0 + 67 <= W - 1);

    if (interior) {
        const float* spb = sp + (i0 - 1) * W + (j0 - 4);
        const float* opb = op + (i0 - 1) * W + (j0 - 4);
        for (int e = tid; e < (TY + 2) * 18; e += 256) {
            int y = e / 18, x4 = e % 18;
            float4 a = *(const float4*)(spb + y * W + x4 * 4);
            float4 o = *(const float4*)(opb + y * W + x4 * 4);
            float sv0 = a.x * inv, sv1 = a.y * inv, sv2 = a.z * inv, sv3 = a.w * inv;
            float4 hv;
            hv.x = hsw(sv0 - hi); hv.y = hsw(sv1 - hi);
            hv.z = hsw(sv2 - hi); hv.w = hsw(sv3 - hi);
            *(float4*)&hs2[y][x4 * 4] = hv;
            *(float4*)&og[y][x4 * 4] = o;
            if (y >= 1 && y <= TY) {
                int c0 = x4 * 4;
                if (c0 + 0 >= 4 && c0 + 0 <= 67) ssn[y - 1][c0 - 4] = sv0;
                if (c0 + 1 >= 4 && c0 + 1 <= 67) ssn[y - 1][c0 - 3] = sv1;
                if (c0 + 2 >= 4 && c0 + 2 <= 67) ssn[y - 1][c0 - 2] = sv2;
                if (c0 + 3 >= 4 && c0 + 3 <= 67) ssn[y - 1][c0 - 1] = sv3;
            }
        }
    } else {
        for (int e = tid; e < (TY + 2) * 72; e += 256) {
            int y = e / 72, x = e % 72;
            int gi = i0 - 1 + y, gj = j0 - 4 + x;
            float h = 0.0f, o = 0.0f;
            if (gi >= 0 && gi < H && gj >= 0 && gj < W) {
                float sv = sp[gi * W + gj] * inv;
                h = hsw(sv - hi);
                o = op[gi * W + gj];
                if (y >= 1 && y <= TY && x >= 4 && x <= 67) ssn[y - 1][x - 4] = sv;
            }
            hs2[y][x] = h;
            og[y][x] = o;
        }
    }
    __syncthreads();

    int yl = threadIdx.y * 4;
    int xl = threadIdx.x;
    float hrow[6], ddr[6], ssr[6];
#pragma unroll
    for (int k = 0; k < 6; k++) {
        float a = hs2[yl + k][xl + 3], bq = hs2[yl + k][xl + 4], c = hs2[yl + k][xl + 5];
        hrow[k] = a + bq + c;
        float oa = og[yl + k][xl + 3], ob = og[yl + k][xl + 4], oc = og[yl + k][xl + 5];
        ddr[k] = oc - oa;
        ssr[k] = oa + 2.0f * ob + oc;
    }

    float bmx = -1e30f, bmn = 1e30f;
    size_t gbase = (size_t)p * HW + (i0 + yl) * W + (j0 + xl);
#pragma unroll
    for (int k = 0; k < 4; k++) {
        float sn = ssn[yl + k][xl];
        float Sh = hs2[yl + k + 1][xl + 4];
        float Sl = hsw(sn - lo);
        float dil = hrow[k] + hrow[k + 1] + hrow[k + 2];
        float pre = sn * (Sh + Sl) + dil * Sl * (1.0f - Sh);
        float sob = 0.5f * fabsf(ddr[k] + 2.0f * ddr[k + 1] + ddr[k + 2]) +
                    0.5f * fabsf(ssr[k + 2] - ssr[k]);
        float r = (1.0f - wg) * pre + wg * sob;
        res[gbase + (size_t)k * W] = r;
        bmx = fmaxf(bmx, r);
        bmn = fminf(bmn, r);
    }

    float vx = wave_max(bmx), vn = wave_min(bmn);
    if ((tid & 63) == 0) { wredx[tid >> 6] = vx; wredn[tid >> 6] = vn; }
    __syncthreads();
    if (tid == 0) {
        int bflat = (blockIdx.z * gridDim.y + blockIdx.y) * gridDim.x + blockIdx.x;
        prmax[bflat] = fmaxf(fmaxf(wredx[0], wredx[1]), fmaxf(wredx[2], wredx[3]));
        prmin[bflat] = fminf(fminf(wredn[0], wredn[1]), fminf(wredn[2], wredn[3]));
    }
}

// final normalize + combine; folds the partial min/max reduction in; float4 I/O
__global__ void K_final(const float* __restrict__ res, const float* __restrict__ prmax,
                        const float* __restrict__ prmin, float* __restrict__ out) {
    int tid = threadIdx.y * 64 + threadIdx.x;

    float vx0 = -1e30f, vn0 = 1e30f, vx1 = -1e30f, vn1 = 1e30f;
    for (int i = tid; i < HBLK; i += 256) {
        vx0 = fmaxf(vx0, prmax[i]);
        vn0 = fminf(vn0, prmin[i]);
        vx1 = fmaxf(vx1, prmax[HBLK + i]);
        vn1 = fminf(vn1, prmin[HBLK + i]);
    }
    vx0 = wave_max(vx0); vn0 = wave_min(vn0);
    vx1 = wave_max(vx1); vn1 = wave_min(vn1);
    __shared__ float sx0[4], sn0[4], sx1[4], sn1[4];
    if ((tid & 63) == 0) {
        int w = tid >> 6;
        sx0[w] = vx0; sn0[w] = vn0; sx1[w] = vx1; sn1[w] = vn1;
    }
    __syncthreads();
    float mx1 = fmaxf(fmaxf(sx0[0], sx0[1]), fmaxf(sx0[2], sx0[3]));
    float mn1 = fminf(fminf(sn0[0], sn0[1]), fminf(sn0[2], sn0[3]));
    float mx2 = fmaxf(fmaxf(sx1[0], sx1[1]), fmaxf(sx1[2], sx1[3]));
    float mn2 = fminf(fminf(sn1[0], sn1[1]), fminf(sn1[2], sn1[3]));
    float is1 = 1.0f / (mx1 - mn1);
    float is2 = 1.0f / (mx2 - mn2);

    int col4 = blockIdx.x * 64 + threadIdx.x;    // float4 column, 0..127
    int i0 = blockIdx.y * 16 + threadIdx.y * 4;  // 4 rows per thread
    int p = blockIdx.z;                          // 0..7
    const float4* r1p = (const float4*)(res + (size_t)p * HW);
    const float4* r2p = (const float4*)(res + (size_t)(p + PPS) * HW);
    float4* outc = (float4*)(out) + (size_t)p * (HW / 4);
    float4* out1 = (float4*)(out) + (size_t)(PPS + p) * (HW / 4);
    float4* out2 = (float4*)(out) + (size_t)(2 * PPS + p) * (HW / 4);

#pragma unroll
    for (int k = 0; k < 4; k++) {
        int row = i0 + k;
        float4 a = r1p[row * (W / 4) + col4];
        float4 b = r2p[row * (W / 4) + col4];
        float4 m1v, m2v, mcv;
        m1v.x = (a.x - mn1) * is1; m1v.y = (a.y - mn1) * is1;
        m1v.z = (a.z - mn1) * is1; m1v.w = (a.w - mn1) * is1;
        m2v.x = (b.x - mn2) * is2; m2v.y = (b.y - mn2) * is2;
        m2v.z = (b.z - mn2) * is2; m2v.w = (b.w - mn2) * is2;
        mcv.x = m1v.x + m2v.x - 2.0f * m1v.x * m2v.x;
        mcv.y = m1v.y + m2v.y - 2.0f * m1v.y * m2v.y;
        mcv.z = m1v.z + m2v.z - 2.0f * m1v.z * m2v.z;
        mcv.w = m1v.w + m2v.w - 2.0f * m1v.w * m2v.w;
        outc[row * (W / 4) + col4] = mcv;
        out1[row * (W / 4) + col4] = m1v;
        out2[row * (W / 4) + col4] = m2v;
    }
}

}  // namespace

extern "C" void kernel_launch(void* const* d_in, const int* in_sizes, int n_in,
                              void* d_out, int out_size, void* d_ws, size_t ws_size,
                              hipStream_t stream) {
    const float* img1 = (const float*)d_in[0];
    const float* img2 = (const float*)d_in[1];
    const float* sg1 = (const float*)d_in[2];
    const float* ew1 = (const float*)d_in[3];
    const float* sg2 = (const float*)d_in[4];
    const float* ew2 = (const float*)d_in[5];
    float* out = (float*)d_out;

    float* A = (float*)d_ws;                             // ping / blurred
    float* B = A + (size_t)NP * HW;                      // pong / res
    float* C = B + (size_t)NP * HW;                      // sup
    unsigned* hist = (unsigned*)(C + (size_t)NP * HW);   // NP*NBINS
    float* medv = (float*)(hist + NP * NBINS);           // 16
    float* mx = medv + NP;
    float* pmax = mx + 2;              // NBLK
    float* prmax = pmax + NBLK;        // NBLK
    float* prmin = prmax + NBLK;       // NBLK

    dim3 blk(64, 4, 1);
    dim3 grdT(W / TX, H / TY, NP);     // dnms / result (4096 blocks)
    dim3 grdS(W / 64, H / STY, NP);    // smooth
    dim3 grdF(W / 256, H / 16, PPS);   // final (512 blocks, float4, 4 rows/thread)
    dim3 mblk(256, 1, 1);

    // adaptive smoothing: 3 iterations  in->A, A->B, B->A  (blurred -> A)
    // first dispatch also zeroes the median histogram
    K_smooth<<<grdS, blk, 0, stream>>>(img1, img2, A, hist);
    K_smooth<<<grdS, blk, 0, stream>>>(A, A + (size_t)PPS * HW, B, nullptr);
    K_smooth<<<grdS, blk, 0, stream>>>(B, B + (size_t)PPS * HW, A, nullptr);

    // fused derivs+NMS+median-hist: A -> sup(C), hist, pmax
    K_dnms<<<grdT, blk, 0, stream>>>(A, C, hist, pmax);

    // per-plane medians + per-set sup max in one dispatch
    K_stats<<<dim3(NP + 2), mblk, 0, stream>>>(hist, pmax, medv, mx);

    // result -> B (+ per-block min/max partials)
    K_result<<<grdT, blk, 0, stream>>>(C, img1, img2, medv, sg1, ew1, sg2, ew2, mx,
                                       B, prmax, prmin);

    // final: fold partial min/max reduce + normalize + combine, float4 I/O
    K_final<<<grdF, blk, 0, stream>>>(B, prmax, prmin, out);
}